// Round 8
// baseline (137.636 us; speedup 1.0000x reference)
//
#include <hip/hip_runtime.h>
#include <stdint.h>
#include <float.h>

#define BLK 256
#define IPT 16                  // owner points per thread (16 chains per ds_read)
#define OWNERS (BLK * IPT)      // 4096 owners per block / per chunk
#define SLICE 128               // candidates per LDS stage (2 KB SoA)
#define KROW 128                // row-side candidate groups (cpb = M/128 = 256)
#define KCOL 64                 // col-side candidate groups (cpb = N/64  = 128)
#define FBLK 64                 // reduce block = 1 wave -> 640 blocks

typedef unsigned long long ull;
typedef unsigned int u32;
typedef float v2f __attribute__((ext_vector_type(2)));

__device__ __forceinline__ v2f fma2(v2f a, v2f b, v2f c) {
    return __builtin_elementwise_fma(a, b, c);   // -> v_pk_fma_f32 (IEEE fma/half)
}

// Monotone float -> uint transform (preserves <, total order) and inverse.
__device__ __forceinline__ unsigned int ford(float f) {
    int b = __float_as_int(f);
    return (b >= 0) ? ((unsigned)b ^ 0x80000000u) : ~(unsigned)b;
}
__device__ __forceinline__ float ford_inv(unsigned int u) {
    int b = (u & 0x80000000u) ? (int)(u ^ 0x80000000u) : (int)~u;
    return __int_as_float(b);
}

// Phase 1 (r8): LDS-pressure test. IPT=16 halves ds_read per pk_fma vs r7
// (theory: scan is LDS-issue/latency-bound at 3 waves/SIMD, not VALU-bound).
// Slots are u32 ford(value) ONLY — no subtile/base tracking in the hot loop;
// the winning GROUP is recovered in phase 2 from the slot index (slot order k
// ascending == candidate-base ascending => first-occurrence ties preserved),
// and the exact index by the verified bit-exact group rescan.
// Zero atomics, zero memset: every slot is written by exactly one block.
__global__ __launch_bounds__(BLK, 3) void nn_scan(
    const float* __restrict__ p, const float* __restrict__ g,
    u32* __restrict__ wsR, u32* __restrict__ wsC,
    float* __restrict__ out, int N, int M)
{
    __shared__ float sbx[SLICE], sby[SLICE], sbz[SLICE], sbw[SLICE];

    if (blockIdx.x == 0 && threadIdx.x == 0) *out = 0.0f;  // fold memset(d_out)

    const int rowChunks = N / OWNERS;              // 2
    const int rowBlocks = rowChunks * KROW;        // 256

    const float* A; const float* B; u32* ws; int id, nK, NO, cpb;
    if ((int)blockIdx.x < rowBlocks) {
        id = blockIdx.x;             A = p; B = g; ws = wsR; nK = KROW; NO = N; cpb = M / KROW;
    } else {
        id = blockIdx.x - rowBlocks; A = g; B = p; ws = wsC; nK = KCOL; NO = M; cpb = N / KCOL;
    }
    const int chunk = id / nK;
    const int kgrp  = id - chunk * nK;
    const int c0 = kgrp * cpb;
    const int nStages = cpb / SLICE;               // row: 2, col: 1

    // ---- owner prologue (registers persist across stages) ----
    const int o0 = chunk * OWNERS + threadIdx.x;
    v2f ax2[IPT], ay2[IPT], az2[IPT];
    float best[IPT];
#pragma unroll
    for (int r = 0; r < IPT; ++r) {
        int o = o0 + r * BLK;
        float axv = -2.0f * A[3 * o];
        float ayv = -2.0f * A[3 * o + 1];
        float azv = -2.0f * A[3 * o + 2];
        ax2[r] = (v2f){axv, axv};
        ay2[r] = (v2f){ayv, ayv};
        az2[r] = (v2f){azv, azv};
        best[r] = FLT_MAX;
    }

    for (int stage = 0; stage < nStages; ++stage) {
        const int gs0 = c0 + stage * SLICE;
        if (stage) __syncthreads();        // readers of previous stage done

        // Stage slice SoA (coords + |B|^2). Explicit fmaf: phase 2 recomputes
        // the identical expression so bit-exact equality holds.
        if (threadIdx.x < SLICE) {
            int s = gs0 + threadIdx.x;
            float bx = B[3 * s], by = B[3 * s + 1], bz = B[3 * s + 2];
            float w = fmaf(bz, bz, fmaf(by, by, bx * bx));
            sbx[threadIdx.x] = bx; sby[threadIdx.x] = by;
            sbz[threadIdx.x] = bz; sbw[threadIdx.x] = w;
        }
        __syncthreads();

#pragma unroll 2
        for (int k = 0; k < SLICE; k += 2) {
            v2f qx = *(const v2f*)&sbx[k];   // k even -> 8B aligned broadcast
            v2f qy = *(const v2f*)&sby[k];
            v2f qz = *(const v2f*)&sbz[k];
            v2f qw = *(const v2f*)&sbw[k];
#pragma unroll
            for (int r = 0; r < IPT; ++r) {
                v2f t = fma2(az2[r], qz, qw);     // 3 pk_fma = 2 candidates
                t = fma2(ay2[r], qy, t);
                t = fma2(ax2[r], qx, t);
                best[r] = fminf(fminf(t.x, t.y), best[r]);   // -> v_min3_f32
            }
        }
    }

    // ---- plain coalesced u32 store to this block's private slot row ----
    u32* dst = ws + (size_t)kgrp * NO;     // ws[kgrp][owner]
#pragma unroll
    for (int r = 0; r < IPT; ++r)
        dst[o0 + r * BLK] = ford(best[r]);
}

// Phase 2: thread-per-owner. K-way u32 min over the owner's slots (coalesced:
// ws[k][o..o+63] = 256 B/wave), strict < keeps the FIRST (smallest-k) group
// among ties; then the verified branchless bit-exact rescan over that group's
// cpb candidates recovers the first index attaining the min; normal dot;
// one atomicAdd per wave.
__global__ __launch_bounds__(FBLK) void nn_reduce(
    const u32* __restrict__ wsR, const u32* __restrict__ wsC,
    const float* __restrict__ p, const float* __restrict__ g,
    const float* __restrict__ pn, const float* __restrict__ gn,
    float* __restrict__ out, int N, int M, float invN, float invM)
{
    int t = blockIdx.x * FBLK + threadIdx.x;
    float c = 0.0f;
    if (t < N + M) {
        const float* A; const float* B; const float* An; const float* Bn;
        const u32* ws; int o, K, NO, cpb; float inv;
        if (t < N) { o = t;     A = p; B = g; An = pn; Bn = gn; ws = wsR;
                     K = KROW; NO = N; cpb = M / KROW; inv = invN; }
        else       { o = t - N; A = g; B = p; An = gn; Bn = pn; ws = wsC;
                     K = KCOL; NO = M; cpb = N / KCOL; inv = invM; }

        u32 bestv = ws[o];                       // slot k=0
        int bestk = 0;
#pragma unroll 4
        for (int k = 1; k < K; ++k) {            // coalesced across lanes
            u32 v = ws[(size_t)k * NO + o];
            bestk = (v < bestv) ? k : bestk;     // strict <: first group wins
            bestv = (v < bestv) ? v : bestv;
        }

        float ax = -2.0f * A[3 * o];
        float ay = -2.0f * A[3 * o + 1];
        float az = -2.0f * A[3 * o + 2];
        float bestf = ford_inv(bestv);
        int b0 = bestk * cpb;

        // Branchless bit-exact first-match rescan over the winning group
        // (identical fmaf chain as the scan's staging+eval => exact equality).
        int idx = 0x7fffffff;
#pragma unroll 4
        for (int j = 0; j < cpb; ++j) {
            int s = b0 + j;
            float bx = B[3 * s], by = B[3 * s + 1], bz = B[3 * s + 2];
            float w = fmaf(bz, bz, fmaf(by, by, bx * bx));
            float v = fmaf(ax, bx, fmaf(ay, by, fmaf(az, bz, w)));
            int cand = (v == bestf) ? s : 0x7fffffff;
            idx = (cand < idx) ? cand : idx;     // ascending -> first match = min s
        }
        if (idx == 0x7fffffff) idx = b0;         // defensive; cannot trigger

        float d = An[3 * o] * Bn[3 * idx] + An[3 * o + 1] * Bn[3 * idx + 1]
                + An[3 * o + 2] * Bn[3 * idx + 2];
        c = (1.0f - d) * inv;
    }
#pragma unroll
    for (int off = 32; off > 0; off >>= 1) c += __shfl_down(c, off, 64);
    if (threadIdx.x == 0) atomicAdd(out, c);
}

// ======================= legacy fallback (r5-verified 3-dispatch path) =======================
#define L_IPT 8
#define L_OWNERS (BLK * L_IPT)
#define L_SLICE 128
#define L_SUB 64

__global__ __launch_bounds__(BLK) void nn_min_dual(
    const float* __restrict__ p, const float* __restrict__ g,
    ull* __restrict__ rowmin, ull* __restrict__ colmin,
    float* __restrict__ out, int rowBlocks, int rowSlices, int colSlices)
{
    __shared__ float sbx[L_SLICE], sby[L_SLICE], sbz[L_SLICE], sbw[L_SLICE];
    if (blockIdx.x == 0 && threadIdx.x == 0) *out = 0.0f;
    const float* A; const float* B; ull* outmin; int id, nSlices;
    if ((int)blockIdx.x < rowBlocks) {
        id = blockIdx.x;             A = p; B = g; outmin = rowmin; nSlices = rowSlices;
    } else {
        id = blockIdx.x - rowBlocks; A = g; B = p; outmin = colmin; nSlices = colSlices;
    }
    const int chunk = id / nSlices;
    const int slice = id - chunk * nSlices;
    const int s0 = slice * L_SLICE;
    if (threadIdx.x < L_SLICE) {
        int s = s0 + threadIdx.x;
        float bx = B[3 * s], by = B[3 * s + 1], bz = B[3 * s + 2];
        float w = fmaf(bz, bz, fmaf(by, by, bx * bx));
        sbx[threadIdx.x] = bx; sby[threadIdx.x] = by;
        sbz[threadIdx.x] = bz; sbw[threadIdx.x] = w;
    }
    const int o0 = chunk * L_OWNERS + threadIdx.x;
    v2f ax2[L_IPT], ay2[L_IPT], az2[L_IPT];
    float best[L_IPT]; int base[L_IPT];
#pragma unroll
    for (int r = 0; r < L_IPT; ++r) {
        int o = o0 + r * BLK;
        float axv = -2.0f * A[3 * o], ayv = -2.0f * A[3 * o + 1], azv = -2.0f * A[3 * o + 2];
        ax2[r] = (v2f){axv, axv}; ay2[r] = (v2f){ayv, ayv}; az2[r] = (v2f){azv, azv};
        best[r] = FLT_MAX; base[r] = s0;
    }
    __syncthreads();
    for (int st = 0; st < L_SLICE; st += L_SUB) {
        float prev[L_IPT];
#pragma unroll
        for (int r = 0; r < L_IPT; ++r) prev[r] = best[r];
#pragma unroll 2
        for (int k = st; k < st + L_SUB; k += 2) {
            v2f qx = *(const v2f*)&sbx[k]; v2f qy = *(const v2f*)&sby[k];
            v2f qz = *(const v2f*)&sbz[k]; v2f qw = *(const v2f*)&sbw[k];
#pragma unroll
            for (int r = 0; r < L_IPT; ++r) {
                v2f t = fma2(az2[r], qz, qw);
                t = fma2(ay2[r], qy, t);
                t = fma2(ax2[r], qx, t);
                best[r] = fminf(fminf(t.x, t.y), best[r]);
            }
        }
#pragma unroll
        for (int r = 0; r < L_IPT; ++r)
            if (best[r] < prev[r]) base[r] = s0 + st;
    }
#pragma unroll
    for (int r = 0; r < L_IPT; ++r) {
        ull packed = ((ull)ford(best[r]) << 32) | (unsigned)base[r];
        atomicMin(&outmin[o0 + r * BLK], packed);
    }
}

__global__ __launch_bounds__(FBLK) void finalize_legacy(
    const ull* __restrict__ rowmin, const ull* __restrict__ colmin,
    const float* __restrict__ p, const float* __restrict__ g,
    const float* __restrict__ pn, const float* __restrict__ gn,
    float* __restrict__ out, int N, int M, float invN, float invM)
{
    int t = blockIdx.x * FBLK + threadIdx.x;
    float c = 0.0f;
    if (t < N + M) {
        const float* A; const float* B; const float* An; const float* Bn;
        ull packed; int o; float inv;
        if (t < N) { o = t;     A = p; B = g; An = pn; Bn = gn; packed = rowmin[o]; inv = invN; }
        else       { o = t - N; A = g; B = p; An = gn; Bn = pn; packed = colmin[o]; inv = invM; }
        float ax = -2.0f * A[3 * o], ay = -2.0f * A[3 * o + 1], az = -2.0f * A[3 * o + 2];
        float bestf = ford_inv((unsigned int)(packed >> 32));
        int b0 = (int)(packed & 0xffffffffull);
        int idx = 0x7fffffff;
#pragma unroll 4
        for (int jj = 0; jj < L_SUB; ++jj) {
            int s = b0 + jj;
            float bx = B[3 * s], by = B[3 * s + 1], bz = B[3 * s + 2];
            float w = fmaf(bz, bz, fmaf(by, by, bx * bx));
            float v = fmaf(ax, bx, fmaf(ay, by, fmaf(az, bz, w)));
            int cand = (v == bestf) ? s : 0x7fffffff;
            idx = (cand < idx) ? cand : idx;
        }
        if (idx == 0x7fffffff) idx = b0;
        float d = An[3 * o] * Bn[3 * idx] + An[3 * o + 1] * Bn[3 * idx + 1]
                + An[3 * o + 2] * Bn[3 * idx + 2];
        c = (1.0f - d) * inv;
    }
#pragma unroll
    for (int off = 32; off > 0; off >>= 1) c += __shfl_down(c, off, 64);
    if (threadIdx.x == 0) atomicAdd(out, c);
}

extern "C" void kernel_launch(void* const* d_in, const int* in_sizes, int n_in,
                              void* d_out, int out_size, void* d_ws, size_t ws_size,
                              hipStream_t stream) {
    const float* p  = (const float*)d_in[0];   // [N,3] predicted points
    const float* pn = (const float*)d_in[1];   // [N,3] predicted normals (unit)
    const float* g  = (const float*)d_in[2];   // [M,3] gt points
    const float* gn = (const float*)d_in[3];   // [M,3] gt normals (unit)
    const int N = in_sizes[0] / 3;             // 8192
    const int M = in_sizes[2] / 3;             // 32768
    float* out = (float*)d_out;

    // ws layout (primary): wsR[KROW][N] | wsC[KCOL][M], u32 -> 12.6 MB (proven fit, r7)
    const size_t wsRn = (size_t)KROW * N;
    const size_t wsCn = (size_t)KCOL * M;
    const size_t needBytes = (wsRn + wsCn) * sizeof(u32);

    const bool geomOK = (N % OWNERS) == 0 && (M % OWNERS) == 0 &&
                        (M % (KROW * SLICE)) == 0 && (N % (KCOL * SLICE)) == 0 &&
                        ((N + M) % FBLK) == 0 && (N % FBLK) == 0;

    if (geomOK && ws_size >= needBytes) {
        // -------- primary: 2 dispatches, no memsets, no atomics in phase 1 --------
        u32* wsR = (u32*)d_ws;
        u32* wsC = wsR + wsRn;
        const int blocks = (N / OWNERS) * KROW + (M / OWNERS) * KCOL;   // 768
        nn_scan<<<blocks, BLK, 0, stream>>>(p, g, wsR, wsC, out, N, M);
        nn_reduce<<<(N + M) / FBLK, FBLK, 0, stream>>>(
            wsR, wsC, p, g, pn, gn, out, N, M, 1.0f / N, 1.0f / M);
    } else {
        // -------- legacy r5-verified 3-dispatch path --------
        ull* rowmin = (ull*)d_ws;
        ull* colmin = rowmin + N;
        hipMemsetAsync(d_ws, 0xFF, (size_t)(N + M) * sizeof(ull), stream);
        const int rowSlices = M / L_SLICE;
        const int colSlices = N / L_SLICE;
        const int rowBlocks = (N / L_OWNERS) * rowSlices;
        const int colBlocks = (M / L_OWNERS) * colSlices;
        nn_min_dual<<<rowBlocks + colBlocks, BLK, 0, stream>>>(
            p, g, rowmin, colmin, out, rowBlocks, rowSlices, colSlices);
        finalize_legacy<<<(N + M + FBLK - 1) / FBLK, FBLK, 0, stream>>>(
            rowmin, colmin, p, g, pn, gn, out, N, M, 1.0f / N, 1.0f / M);
    }
}